// Round 5
// baseline (200.950 us; speedup 1.0000x reference)
//
#include <hip/hip_runtime.h>
#include <hip/hip_bf16.h>

typedef _Float16 half8 __attribute__((ext_vector_type(8)));
typedef _Float16 half4_t __attribute__((ext_vector_type(4)));
typedef _Float16 half2_t __attribute__((ext_vector_type(2)));
typedef float floatx4 __attribute__((ext_vector_type(4)));
typedef float floatx2 __attribute__((ext_vector_type(2)));

#define MFMA16(a, b, c) __builtin_amdgcn_mfma_f32_16x16x32_f16(a, b, c, 0, 0, 0)
#define MASKVAL (-30000.0f)
// 1/sqrt(128) * log2(e), folded into wqt during prep
#define QSCALE 0.1275261529f

// ---------------------------------------------------------------------------
// Kernel 1: coalesced LDS-tiled weight transpose + fp32->fp16 convert.
// QSCALE folded into wqt.
// ---------------------------------------------------------------------------
__global__ __launch_bounds__(256) void wprep(
    const float* __restrict__ wq, const float* __restrict__ wk,
    const float* __restrict__ wv, const float* __restrict__ wo,
    _Float16* __restrict__ wqt, _Float16* __restrict__ wkt,
    _Float16* __restrict__ wvt, _Float16* __restrict__ wot) {
  __shared__ float T[32][36];
  int bx = blockIdx.x, tid = threadIdx.x;
  const float* src;
  _Float16* dst;
  int R, C, r0, c0;
  float sc = 1.0f;
  if (bx < 384) {
    int p = bx >> 7, t = bx & 127;
    src = (p == 0) ? wq : (p == 1) ? wk : wv;
    dst = (p == 0) ? wqt : (p == 1) ? wkt : wvt;
    if (p == 0) sc = QSCALE;
    R = 1024; C = 128;
    r0 = (t & 31) * 32; c0 = (t >> 5) * 32;
  } else {
    int t = bx - 384;
    src = wo; dst = wot;
    R = 128; C = 1024;
    r0 = (t & 3) * 32; c0 = (t >> 2) * 32;
  }
  {
    int row = tid >> 3, c4 = (tid & 7) * 4;
    float4 f = *(const float4*)&src[(size_t)(r0 + row) * C + c0 + c4];
    T[row][c4] = f.x; T[row][c4 + 1] = f.y; T[row][c4 + 2] = f.z; T[row][c4 + 3] = f.w;
  }
  __syncthreads();
  {
    int cc = tid >> 3, r4 = (tid & 7) * 4;
    half4_t h;
    h[0] = (_Float16)(T[r4 + 0][cc] * sc);
    h[1] = (_Float16)(T[r4 + 1][cc] * sc);
    h[2] = (_Float16)(T[r4 + 2][cc] * sc);
    h[3] = (_Float16)(T[r4 + 3][cc] * sc);
    *(half4_t*)&dst[(size_t)(c0 + cc) * R + r0 + r4] = h;
  }
}

// ---------------------------------------------------------------------------
// Kernel 2: QKV projection, grid (128 m-tiles, 3 proj). x converted fp32->fp16
// in-register during A-staging. V written transposed Vt[(b*128+h)*2048+s].
// ---------------------------------------------------------------------------
__global__ __launch_bounds__(256) void qkv_gemm(
    const float* __restrict__ x, const _Float16* __restrict__ wqt,
    const _Float16* __restrict__ wkt, const _Float16* __restrict__ wvt,
    _Float16* __restrict__ Qh, _Float16* __restrict__ Kh,
    _Float16* __restrict__ Vt) {
  __shared__ _Float16 A_lds[64 * 72];
  __shared__ _Float16 B_lds[128 * 72];
  int tid = threadIdx.x;
  int w = tid >> 6, lane = tid & 63, quad = lane >> 4, l16 = lane & 15;
  int m0 = blockIdx.x * 64;
  int proj = blockIdx.y;
  const _Float16* wt = (proj == 0) ? wqt : (proj == 1) ? wkt : wvt;
  floatx4 zero = {0.f, 0.f, 0.f, 0.f};
  floatx4 acc[8];
#pragma unroll
  for (int t = 0; t < 8; t++) acc[t] = zero;

  int arow = tid >> 2, akk = (tid & 3) * 16;
  int bn = tid >> 1, bkk = (tid & 1) * 32;

  for (int k0 = 0; k0 < 1024; k0 += 64) {
    {
      const float* s = x + (size_t)(m0 + arow) * 1024 + k0 + akk;
      float4 f0 = *(const float4*)(s);
      float4 f1 = *(const float4*)(s + 4);
      float4 f2 = *(const float4*)(s + 8);
      float4 f3 = *(const float4*)(s + 12);
      half8 h0, h1;
      h0[0] = (_Float16)f0.x; h0[1] = (_Float16)f0.y; h0[2] = (_Float16)f0.z; h0[3] = (_Float16)f0.w;
      h0[4] = (_Float16)f1.x; h0[5] = (_Float16)f1.y; h0[6] = (_Float16)f1.z; h0[7] = (_Float16)f1.w;
      h1[0] = (_Float16)f2.x; h1[1] = (_Float16)f2.y; h1[2] = (_Float16)f2.z; h1[3] = (_Float16)f2.w;
      h1[4] = (_Float16)f3.x; h1[5] = (_Float16)f3.y; h1[6] = (_Float16)f3.z; h1[7] = (_Float16)f3.w;
      *(half8*)&A_lds[arow * 72 + akk] = h0;
      *(half8*)&A_lds[arow * 72 + akk + 8] = h1;
    }
#pragma unroll
    for (int i = 0; i < 4; i++)
      *(half8*)&B_lds[bn * 72 + bkk + i * 8] =
          *(const half8*)&wt[(size_t)bn * 1024 + k0 + bkk + i * 8];
    __syncthreads();
    half8 a[2];
#pragma unroll
    for (int c = 0; c < 2; c++) a[c] = *(const half8*)&A_lds[(w * 16 + l16) * 72 + c * 32 + quad * 8];
#pragma unroll
    for (int t = 0; t < 8; t++)
#pragma unroll
      for (int c = 0; c < 2; c++) {
        half8 b = *(const half8*)&B_lds[(t * 16 + l16) * 72 + c * 32 + quad * 8];
        acc[t] = MFMA16(a[c], b, acc[t]);
      }
    __syncthreads();
  }
#pragma unroll
  for (int t = 0; t < 8; t++)
#pragma unroll
    for (int r = 0; r < 4; r++) {
      int row = m0 + w * 16 + quad * 4 + r;
      int col = t * 16 + l16;
      _Float16 v = (_Float16)acc[t][r];
      if (proj == 0)
        Qh[(size_t)row * 128 + col] = v;
      else if (proj == 1)
        Kh[(size_t)row * 128 + col] = v;
      else {
        int bb = row >> 11, s = row & 2047;
        Vt[((size_t)(bb * 128 + col)) * 2048 + s] = v;
      }
    }
}

// ---------------------------------------------------------------------------
// Kernel 3: flash-attention partial, one 128-key chunk per block. NO K/V LDS
// staging, NO barriers: K/V fragments read directly from global (L2-resident).
// LDS holds only the wave-private P transpose (17.4 KB/block -> ~4 blocks/CU,
// ~16 waves/CU; all ~1088 live blocks co-resident). Branchless diagonal mask.
// ---------------------------------------------------------------------------
__global__ __launch_bounds__(256) void attn_partial(
    const _Float16* __restrict__ Qh, const _Float16* __restrict__ Kh,
    const _Float16* __restrict__ Vt, _Float16* __restrict__ Opart,
    float* __restrict__ Ml) {
  __shared__ _Float16 P_lds[4 * 16 * 136];
  int tid = threadIdx.x;
  int w = tid >> 6, lane = tid & 63, quad = lane >> 4, l16 = lane & 15;
  int kc = blockIdx.x;
  int qt = 31 - (int)blockIdx.y;  // heavy q-tiles dispatch first
  int b = blockIdx.z;
  int nkc = (qt + 2) >> 1;        // ceil((qt*64+64)/128)
  if (kc >= nkc) return;
  int q0 = qt * 64;
  int k0 = kc * 128;
  int qw0 = q0 + w * 16;
  int sidx = (b * 32 + qt) * 16 + kc;

  const _Float16* Kb = Kh + (size_t)b * 2048 * 128;
  const _Float16* Vb = Vt + (size_t)b * 128 * 2048;

  half8 aq[4];
  {
    const _Float16* qbase = Qh + (size_t)(b * 2048 + qw0 + l16) * 128;
#pragma unroll
    for (int c = 0; c < 4; c++) aq[c] = *(const half8*)&qbase[c * 32 + quad * 8];
  }

  // QK^T: 8 subtiles of 16 keys, fragments straight from global
  floatx4 zero = {0.f, 0.f, 0.f, 0.f};
  floatx4 sa[8];
#pragma unroll
  for (int t = 0; t < 8; t++) sa[t] = zero;
#pragma unroll
  for (int t = 0; t < 8; t++)
#pragma unroll
    for (int c = 0; c < 4; c++) {
      half8 bk = *(const half8*)&Kb[(size_t)(k0 + t * 16 + l16) * 128 + c * 32 + quad * 8];
      sa[t] = MFMA16(aq[c], bk, sa[t]);
    }

  // softmax over this chunk (branchless causal mask; exp2 underflow -> 0)
  float m_r[4], l_r[4];
#pragma unroll
  for (int r = 0; r < 4; r++) {
    int query = qw0 + quad * 4 + r;
    float mx = MASKVAL;
#pragma unroll
    for (int t = 0; t < 8; t++) {
      float s = (k0 + t * 16 + l16 > query) ? MASKVAL : sa[t][r];
      sa[t][r] = s;
      mx = fmaxf(mx, s);
    }
#pragma unroll
    for (int off = 1; off < 16; off <<= 1) mx = fmaxf(mx, __shfl_xor(mx, off));
    float rs = 0.f;
#pragma unroll
    for (int t = 0; t < 8; t++) {
      float e = exp2f(sa[t][r] - mx);
      sa[t][r] = e;
      rs += e;
    }
#pragma unroll
    for (int off = 1; off < 16; off <<= 1) rs += __shfl_xor(rs, off);
    m_r[r] = mx;
    l_r[r] = rs;
  }

  // P: C-layout -> LDS -> A-layout (wave-private region, no barrier)
  _Float16* P = P_lds + w * 16 * 136;
#pragma unroll
  for (int r = 0; r < 4; r++)
#pragma unroll
    for (int t = 0; t < 8; t++)
      P[(quad * 4 + r) * 136 + t * 16 + l16] = (_Float16)sa[t][r];

  // PV: V fragments straight from global
  floatx4 O[8];
#pragma unroll
  for (int t = 0; t < 8; t++) O[t] = zero;
#pragma unroll
  for (int c2 = 0; c2 < 4; c2++) {
    half8 ap = *(const half8*)&P[l16 * 136 + c2 * 32 + quad * 8];
#pragma unroll
    for (int t = 0; t < 8; t++) {
      half8 bv = *(const half8*)&Vb[(size_t)(t * 16 + l16) * 2048 + k0 + c2 * 32 + quad * 8];
      O[t] = MFMA16(ap, bv, O[t]);
    }
  }

  size_t obase = (size_t)sidx * 8192;
#pragma unroll
  for (int t = 0; t < 8; t++)
#pragma unroll
    for (int r = 0; r < 4; r++)
      Opart[obase + (size_t)(w * 16 + quad * 4 + r) * 128 + t * 16 + l16] = (_Float16)O[t][r];
  if (l16 == 0)
#pragma unroll
    for (int r = 0; r < 4; r++) {
      int row = w * 16 + quad * 4 + r;
      floatx2 ml;
      ml[0] = m_r[r];
      ml[1] = l_r[r];
      *(floatx2*)&Ml[(size_t)sidx * 128 + row * 2] = ml;
    }
}

// ---------------------------------------------------------------------------
// Kernel 3b: combine partials (up to 16/row). One wave per query row.
// ---------------------------------------------------------------------------
__global__ __launch_bounds__(256) void attn_combine(
    const _Float16* __restrict__ Opart, const float* __restrict__ Ml,
    _Float16* __restrict__ ctx) {
  int tid = threadIdx.x;
  int w = tid >> 6, lane = tid & 63;
  int row = blockIdx.x * 4 + w;
  int b = row >> 11, s = row & 2047;
  int qt = s >> 6, ri = s & 63;
  int nkc = (qt + 2) >> 1;
  int sidx0 = (b * 32 + qt) * 16;
  float M = MASKVAL;
  for (int i = 0; i < nkc; i++)
    M = fmaxf(M, Ml[(size_t)(sidx0 + i) * 128 + ri * 2]);
  float L = 0.f, a0 = 0.f, a1 = 0.f;
  for (int i = 0; i < nkc; i++) {
    float mi = Ml[(size_t)(sidx0 + i) * 128 + ri * 2];
    float li = Ml[(size_t)(sidx0 + i) * 128 + ri * 2 + 1];
    float sc = exp2f(mi - M);
    L += li * sc;
    half2_t o = *(const half2_t*)&Opart[(size_t)(sidx0 + i) * 8192 + (size_t)ri * 128 + lane * 2];
    a0 += sc * (float)o[0];
    a1 += sc * (float)o[1];
  }
  float inv = 1.f / L;
  half2_t hv;
  hv[0] = (_Float16)(a0 * inv);
  hv[1] = (_Float16)(a1 * inv);
  *(half2_t*)&ctx[(size_t)row * 128 + lane * 2] = hv;
}

// ---------------------------------------------------------------------------
// Kernel 4: out projection ctx[8192,128] x wo[128,1024] -> fp32 out.
// ---------------------------------------------------------------------------
__global__ __launch_bounds__(256) void out_gemm(
    const _Float16* __restrict__ ctx, const _Float16* __restrict__ wot,
    float* __restrict__ out) {
  __shared__ _Float16 A_lds[64 * 136];
  __shared__ _Float16 B_lds[128 * 136];
  int tid = threadIdx.x;
  int w = tid >> 6, lane = tid & 63, quad = lane >> 4, l16 = lane & 15;
  int m0 = blockIdx.x * 64, n0 = blockIdx.y * 128;
  {
    int row = tid >> 2, kk = (tid & 3) * 32;
#pragma unroll
    for (int i = 0; i < 4; i++)
      *(half8*)&A_lds[row * 136 + kk + i * 8] =
          *(const half8*)&ctx[(size_t)(m0 + row) * 128 + kk + i * 8];
  }
  {
    int n = tid >> 1, kk = (tid & 1) * 64;
#pragma unroll
    for (int i = 0; i < 8; i++)
      *(half8*)&B_lds[n * 136 + kk + i * 8] =
          *(const half8*)&wot[(size_t)(n0 + n) * 128 + kk + i * 8];
  }
  __syncthreads();
  floatx4 zero = {0.f, 0.f, 0.f, 0.f};
  floatx4 acc[8];
#pragma unroll
  for (int t = 0; t < 8; t++) acc[t] = zero;
  half8 a[4];
#pragma unroll
  for (int c = 0; c < 4; c++) a[c] = *(const half8*)&A_lds[(w * 16 + l16) * 136 + c * 32 + quad * 8];
#pragma unroll
  for (int t = 0; t < 8; t++)
#pragma unroll
    for (int c = 0; c < 4; c++) {
      half8 b = *(const half8*)&B_lds[(t * 16 + l16) * 136 + c * 32 + quad * 8];
      acc[t] = MFMA16(a[c], b, acc[t]);
    }
#pragma unroll
  for (int t = 0; t < 8; t++)
#pragma unroll
    for (int r = 0; r < 4; r++) {
      int row = m0 + w * 16 + quad * 4 + r;
      out[(size_t)row * 1024 + n0 + t * 16 + l16] = acc[t][r];
    }
}

// ---------------------------------------------------------------------------
extern "C" void kernel_launch(void* const* d_in, const int* in_sizes, int n_in,
                              void* d_out, int out_size, void* d_ws, size_t ws_size,
                              hipStream_t stream) {
  const float* x = (const float*)d_in[0];
  const float* wq = (const float*)d_in[1];
  const float* wk = (const float*)d_in[2];
  const float* wv = (const float*)d_in[3];
  const float* wo = (const float*)d_in[4];
  char* ws = (char*)d_ws;
  _Float16* wqt = (_Float16*)(ws + 0);
  _Float16* wkt = (_Float16*)(ws + 262144);
  _Float16* wvt = (_Float16*)(ws + 524288);
  _Float16* wot = (_Float16*)(ws + 786432);
  _Float16* Qh  = (_Float16*)(ws + 1048576);              // 2 MB
  _Float16* Kh  = (_Float16*)(ws + 3145728);              // 2 MB
  _Float16* Vt  = (_Float16*)(ws + 5242880);              // 2 MB
  _Float16* ctxh = (_Float16*)(ws + 7340032);             // 2 MB
  _Float16* Opart = (_Float16*)(ws + 9437184);            // 2048 x 16 KB = 32 MB
  float* Ml = (float*)(ws + 42991616);                    // 1 MB
  float* out = (float*)d_out;

  wprep<<<512, 256, 0, stream>>>(wq, wk, wv, wo, wqt, wkt, wvt, wot);
  qkv_gemm<<<dim3(128, 3), 256, 0, stream>>>(x, wqt, wkt, wvt, Qh, Kh, Vt);
  attn_partial<<<dim3(16, 32, 4), 256, 0, stream>>>(Qh, Kh, Vt, Opart, Ml);
  attn_combine<<<2048, 256, 0, stream>>>(Opart, Ml, ctxh);
  out_gemm<<<dim3(128, 8), 256, 0, stream>>>(ctxh, wot, out);
}

// Round 6
// 181.599 us; speedup vs baseline: 1.1066x; 1.1066x over previous
//
#include <hip/hip_runtime.h>
#include <hip/hip_bf16.h>

typedef _Float16 half8 __attribute__((ext_vector_type(8)));
typedef _Float16 half4_t __attribute__((ext_vector_type(4)));
typedef _Float16 half2_t __attribute__((ext_vector_type(2)));
typedef float floatx4 __attribute__((ext_vector_type(4)));
typedef float floatx2 __attribute__((ext_vector_type(2)));

#define MFMA16(a, b, c) __builtin_amdgcn_mfma_f32_16x16x32_f16(a, b, c, 0, 0, 0)
#define MASKVAL (-30000.0f)
// 1/sqrt(128) * log2(e), folded into wqt during prep
#define QSCALE 0.1275261529f

// ---------------------------------------------------------------------------
// Kernel 1: coalesced LDS-tiled weight transpose + fp32->fp16 convert.
// ---------------------------------------------------------------------------
__global__ __launch_bounds__(256) void wprep(
    const float* __restrict__ wq, const float* __restrict__ wk,
    const float* __restrict__ wv, const float* __restrict__ wo,
    _Float16* __restrict__ wqt, _Float16* __restrict__ wkt,
    _Float16* __restrict__ wvt, _Float16* __restrict__ wot) {
  __shared__ float T[32][36];
  int bx = blockIdx.x, tid = threadIdx.x;
  const float* src;
  _Float16* dst;
  int R, C, r0, c0;
  float sc = 1.0f;
  if (bx < 384) {
    int p = bx >> 7, t = bx & 127;
    src = (p == 0) ? wq : (p == 1) ? wk : wv;
    dst = (p == 0) ? wqt : (p == 1) ? wkt : wvt;
    if (p == 0) sc = QSCALE;
    R = 1024; C = 128;
    r0 = (t & 31) * 32; c0 = (t >> 5) * 32;
  } else {
    int t = bx - 384;
    src = wo; dst = wot;
    R = 128; C = 1024;
    r0 = (t & 3) * 32; c0 = (t >> 2) * 32;
  }
  {
    int row = tid >> 3, c4 = (tid & 7) * 4;
    float4 f = *(const float4*)&src[(size_t)(r0 + row) * C + c0 + c4];
    T[row][c4] = f.x; T[row][c4 + 1] = f.y; T[row][c4 + 2] = f.z; T[row][c4 + 3] = f.w;
  }
  __syncthreads();
  {
    int cc = tid >> 3, r4 = (tid & 7) * 4;
    half4_t h;
    h[0] = (_Float16)(T[r4 + 0][cc] * sc);
    h[1] = (_Float16)(T[r4 + 1][cc] * sc);
    h[2] = (_Float16)(T[r4 + 2][cc] * sc);
    h[3] = (_Float16)(T[r4 + 3][cc] * sc);
    *(half4_t*)&dst[(size_t)(c0 + cc) * R + r0 + r4] = h;
  }
}

// ---------------------------------------------------------------------------
// Kernel 2: QKV projection, grid (128 m-tiles, 3 proj). x converted fp32->fp16
// in-register during A-staging. V written transposed Vt[(b*128+h)*2048+s].
// ---------------------------------------------------------------------------
__global__ __launch_bounds__(256) void qkv_gemm(
    const float* __restrict__ x, const _Float16* __restrict__ wqt,
    const _Float16* __restrict__ wkt, const _Float16* __restrict__ wvt,
    _Float16* __restrict__ Qh, _Float16* __restrict__ Kh,
    _Float16* __restrict__ Vt) {
  __shared__ _Float16 A_lds[64 * 72];
  __shared__ _Float16 B_lds[128 * 72];
  int tid = threadIdx.x;
  int w = tid >> 6, lane = tid & 63, quad = lane >> 4, l16 = lane & 15;
  int m0 = blockIdx.x * 64;
  int proj = blockIdx.y;
  const _Float16* wt = (proj == 0) ? wqt : (proj == 1) ? wkt : wvt;
  floatx4 zero = {0.f, 0.f, 0.f, 0.f};
  floatx4 acc[8];
#pragma unroll
  for (int t = 0; t < 8; t++) acc[t] = zero;

  int arow = tid >> 2, akk = (tid & 3) * 16;
  int bn = tid >> 1, bkk = (tid & 1) * 32;

  for (int k0 = 0; k0 < 1024; k0 += 64) {
    {
      const float* s = x + (size_t)(m0 + arow) * 1024 + k0 + akk;
      float4 f0 = *(const float4*)(s);
      float4 f1 = *(const float4*)(s + 4);
      float4 f2 = *(const float4*)(s + 8);
      float4 f3 = *(const float4*)(s + 12);
      half8 h0, h1;
      h0[0] = (_Float16)f0.x; h0[1] = (_Float16)f0.y; h0[2] = (_Float16)f0.z; h0[3] = (_Float16)f0.w;
      h0[4] = (_Float16)f1.x; h0[5] = (_Float16)f1.y; h0[6] = (_Float16)f1.z; h0[7] = (_Float16)f1.w;
      h1[0] = (_Float16)f2.x; h1[1] = (_Float16)f2.y; h1[2] = (_Float16)f2.z; h1[3] = (_Float16)f2.w;
      h1[4] = (_Float16)f3.x; h1[5] = (_Float16)f3.y; h1[6] = (_Float16)f3.z; h1[7] = (_Float16)f3.w;
      *(half8*)&A_lds[arow * 72 + akk] = h0;
      *(half8*)&A_lds[arow * 72 + akk + 8] = h1;
    }
#pragma unroll
    for (int i = 0; i < 4; i++)
      *(half8*)&B_lds[bn * 72 + bkk + i * 8] =
          *(const half8*)&wt[(size_t)bn * 1024 + k0 + bkk + i * 8];
    __syncthreads();
    half8 a[2];
#pragma unroll
    for (int c = 0; c < 2; c++) a[c] = *(const half8*)&A_lds[(w * 16 + l16) * 72 + c * 32 + quad * 8];
#pragma unroll
    for (int t = 0; t < 8; t++)
#pragma unroll
      for (int c = 0; c < 2; c++) {
        half8 b = *(const half8*)&B_lds[(t * 16 + l16) * 72 + c * 32 + quad * 8];
        acc[t] = MFMA16(a[c], b, acc[t]);
      }
    __syncthreads();
  }
#pragma unroll
  for (int t = 0; t < 8; t++)
#pragma unroll
    for (int r = 0; r < 4; r++) {
      int row = m0 + w * 16 + quad * 4 + r;
      int col = t * 16 + l16;
      _Float16 v = (_Float16)acc[t][r];
      if (proj == 0)
        Qh[(size_t)row * 128 + col] = v;
      else if (proj == 1)
        Kh[(size_t)row * 128 + col] = v;
      else {
        int bb = row >> 11, s = row & 2047;
        Vt[((size_t)(bb * 128 + col)) * 2048 + s] = v;
      }
    }
}

// ---------------------------------------------------------------------------
// Kernel 3: flash-attention partial, one 128-key chunk per block.
// K staged in LDS (34.8 KB -> 4 blocks/CU); after softmax the K region is
// reused for P (one barrier). V read direct from global (L2-resident),
// interleaved with PV MFMAs. __launch_bounds__(256,4) pins VGPR<=128 so
// V loads stay in flight. ~1088 live blocks ~= one co-resident cohort.
// ---------------------------------------------------------------------------
__global__ __launch_bounds__(256, 4) void attn_partial(
    const _Float16* __restrict__ Qh, const _Float16* __restrict__ Kh,
    const _Float16* __restrict__ Vt, _Float16* __restrict__ Opart,
    float* __restrict__ Ml) {
  __shared__ _Float16 K_lds[128 * 136];  // K chunk; reused for P after barrier
  int tid = threadIdx.x;
  int w = tid >> 6, lane = tid & 63, quad = lane >> 4, l16 = lane & 15;
  int kc = blockIdx.x;
  int qt = 31 - (int)blockIdx.y;  // heavy q-tiles dispatch first
  int b = blockIdx.z;
  int nkc = (qt + 2) >> 1;        // ceil((qt*64+64)/128)
  if (kc >= nkc) return;
  int q0 = qt * 64;
  int k0 = kc * 128;
  int qw0 = q0 + w * 16;
  int sidx = (b * 32 + qt) * 16 + kc;

  const _Float16* Kb = Kh + (size_t)b * 2048 * 128;
  const _Float16* Vb = Vt + (size_t)b * 128 * 2048;

  // stage K chunk (128 keys x 128 feat), coalesced
  {
    int row = tid >> 1, koff = (tid & 1) * 64;
#pragma unroll
    for (int i = 0; i < 8; i++)
      *(half8*)&K_lds[row * 136 + koff + i * 8] =
          *(const half8*)&Kb[(size_t)(k0 + row) * 128 + koff + i * 8];
  }

  half8 aq[4];
  {
    const _Float16* qbase = Qh + (size_t)(b * 2048 + qw0 + l16) * 128;
#pragma unroll
    for (int c = 0; c < 4; c++) aq[c] = *(const half8*)&qbase[c * 32 + quad * 8];
  }
  __syncthreads();

  // QK^T: 8 subtiles of 16 keys from LDS
  floatx4 zero = {0.f, 0.f, 0.f, 0.f};
  floatx4 sa[8];
#pragma unroll
  for (int t = 0; t < 8; t++) sa[t] = zero;
#pragma unroll
  for (int t = 0; t < 8; t++)
#pragma unroll
    for (int c = 0; c < 4; c++) {
      half8 bk = *(const half8*)&K_lds[(t * 16 + l16) * 136 + c * 32 + quad * 8];
      sa[t] = MFMA16(aq[c], bk, sa[t]);
    }

  // softmax over this chunk (branchless causal mask; exp2 underflow -> 0)
  float m_r[4], l_r[4];
#pragma unroll
  for (int r = 0; r < 4; r++) {
    int query = qw0 + quad * 4 + r;
    float mx = MASKVAL;
#pragma unroll
    for (int t = 0; t < 8; t++) {
      float s = (k0 + t * 16 + l16 > query) ? MASKVAL : sa[t][r];
      sa[t][r] = s;
      mx = fmaxf(mx, s);
    }
#pragma unroll
    for (int off = 1; off < 16; off <<= 1) mx = fmaxf(mx, __shfl_xor(mx, off));
    float rs = 0.f;
#pragma unroll
    for (int t = 0; t < 8; t++) {
      float e = exp2f(sa[t][r] - mx);
      sa[t][r] = e;
      rs += e;
    }
#pragma unroll
    for (int off = 1; off < 16; off <<= 1) rs += __shfl_xor(rs, off);
    m_r[r] = mx;
    l_r[r] = rs;
  }

  __syncthreads();  // all waves done reading K; reuse K_lds for P

  // P: C-layout -> LDS -> A-layout (wave-owned 16-row region of K_lds)
  _Float16* P = K_lds + w * 16 * 136;
#pragma unroll
  for (int r = 0; r < 4; r++)
#pragma unroll
    for (int t = 0; t < 8; t++)
      P[(quad * 4 + r) * 136 + t * 16 + l16] = (_Float16)sa[t][r];

  // PV: V fragments direct from global, interleaved with MFMAs
  floatx4 O[8];
#pragma unroll
  for (int t = 0; t < 8; t++) O[t] = zero;
#pragma unroll
  for (int c2 = 0; c2 < 4; c2++) {
    half8 ap = *(const half8*)&P[l16 * 136 + c2 * 32 + quad * 8];
#pragma unroll
    for (int t = 0; t < 8; t++) {
      half8 bv = *(const half8*)&Vb[(size_t)(t * 16 + l16) * 2048 + k0 + c2 * 32 + quad * 8];
      O[t] = MFMA16(ap, bv, O[t]);
    }
  }

  size_t obase = (size_t)sidx * 8192;
#pragma unroll
  for (int t = 0; t < 8; t++)
#pragma unroll
    for (int r = 0; r < 4; r++)
      Opart[obase + (size_t)(w * 16 + quad * 4 + r) * 128 + t * 16 + l16] = (_Float16)O[t][r];
  if (l16 == 0)
#pragma unroll
    for (int r = 0; r < 4; r++) {
      int row = w * 16 + quad * 4 + r;
      floatx2 ml;
      ml[0] = m_r[r];
      ml[1] = l_r[r];
      *(floatx2*)&Ml[(size_t)sidx * 128 + row * 2] = ml;
    }
}

// ---------------------------------------------------------------------------
// Kernel 3b: combine partials (up to 16/row). One wave per query row.
// ---------------------------------------------------------------------------
__global__ __launch_bounds__(256) void attn_combine(
    const _Float16* __restrict__ Opart, const float* __restrict__ Ml,
    _Float16* __restrict__ ctx) {
  int tid = threadIdx.x;
  int w = tid >> 6, lane = tid & 63;
  int row = blockIdx.x * 4 + w;
  int b = row >> 11, s = row & 2047;
  int qt = s >> 6, ri = s & 63;
  int nkc = (qt + 2) >> 1;
  int sidx0 = (b * 32 + qt) * 16;
  float M = MASKVAL;
  for (int i = 0; i < nkc; i++)
    M = fmaxf(M, Ml[(size_t)(sidx0 + i) * 128 + ri * 2]);
  float L = 0.f, a0 = 0.f, a1 = 0.f;
  for (int i = 0; i < nkc; i++) {
    float mi = Ml[(size_t)(sidx0 + i) * 128 + ri * 2];
    float li = Ml[(size_t)(sidx0 + i) * 128 + ri * 2 + 1];
    float sc = exp2f(mi - M);
    L += li * sc;
    half2_t o = *(const half2_t*)&Opart[(size_t)(sidx0 + i) * 8192 + (size_t)ri * 128 + lane * 2];
    a0 += sc * (float)o[0];
    a1 += sc * (float)o[1];
  }
  float inv = 1.f / L;
  half2_t hv;
  hv[0] = (_Float16)(a0 * inv);
  hv[1] = (_Float16)(a1 * inv);
  *(half2_t*)&ctx[(size_t)row * 128 + lane * 2] = hv;
}

// ---------------------------------------------------------------------------
// Kernel 4: out projection ctx[8192,128] x wo[128,1024] -> fp32 out.
// ---------------------------------------------------------------------------
__global__ __launch_bounds__(256) void out_gemm(
    const _Float16* __restrict__ ctx, const _Float16* __restrict__ wot,
    float* __restrict__ out) {
  __shared__ _Float16 A_lds[64 * 136];
  __shared__ _Float16 B_lds[128 * 136];
  int tid = threadIdx.x;
  int w = tid >> 6, lane = tid & 63, quad = lane >> 4, l16 = lane & 15;
  int m0 = blockIdx.x * 64, n0 = blockIdx.y * 128;
  {
    int row = tid >> 2, kk = (tid & 3) * 32;
#pragma unroll
    for (int i = 0; i < 4; i++)
      *(half8*)&A_lds[row * 136 + kk + i * 8] =
          *(const half8*)&ctx[(size_t)(m0 + row) * 128 + kk + i * 8];
  }
  {
    int n = tid >> 1, kk = (tid & 1) * 64;
#pragma unroll
    for (int i = 0; i < 8; i++)
      *(half8*)&B_lds[n * 136 + kk + i * 8] =
          *(const half8*)&wot[(size_t)(n0 + n) * 128 + kk + i * 8];
  }
  __syncthreads();
  floatx4 zero = {0.f, 0.f, 0.f, 0.f};
  floatx4 acc[8];
#pragma unroll
  for (int t = 0; t < 8; t++) acc[t] = zero;
  half8 a[4];
#pragma unroll
  for (int c = 0; c < 4; c++) a[c] = *(const half8*)&A_lds[(w * 16 + l16) * 136 + c * 32 + quad * 8];
#pragma unroll
  for (int t = 0; t < 8; t++)
#pragma unroll
    for (int c = 0; c < 4; c++) {
      half8 b = *(const half8*)&B_lds[(t * 16 + l16) * 136 + c * 32 + quad * 8];
      acc[t] = MFMA16(a[c], b, acc[t]);
    }
#pragma unroll
  for (int t = 0; t < 8; t++)
#pragma unroll
    for (int r = 0; r < 4; r++) {
      int row = m0 + w * 16 + quad * 4 + r;
      out[(size_t)row * 1024 + n0 + t * 16 + l16] = acc[t][r];
    }
}

// ---------------------------------------------------------------------------
extern "C" void kernel_launch(void* const* d_in, const int* in_sizes, int n_in,
                              void* d_out, int out_size, void* d_ws, size_t ws_size,
                              hipStream_t stream) {
  const float* x = (const float*)d_in[0];
  const float* wq = (const float*)d_in[1];
  const float* wk = (const float*)d_in[2];
  const float* wv = (const float*)d_in[3];
  const float* wo = (const float*)d_in[4];
  char* ws = (char*)d_ws;
  _Float16* wqt = (_Float16*)(ws + 0);
  _Float16* wkt = (_Float16*)(ws + 262144);
  _Float16* wvt = (_Float16*)(ws + 524288);
  _Float16* wot = (_Float16*)(ws + 786432);
  _Float16* Qh  = (_Float16*)(ws + 1048576);              // 2 MB
  _Float16* Kh  = (_Float16*)(ws + 3145728);              // 2 MB
  _Float16* Vt  = (_Float16*)(ws + 5242880);              // 2 MB
  _Float16* ctxh = (_Float16*)(ws + 7340032);             // 2 MB
  _Float16* Opart = (_Float16*)(ws + 9437184);            // 2048 x 16 KB = 32 MB
  float* Ml = (float*)(ws + 42991616);                    // 1 MB
  float* out = (float*)d_out;

  wprep<<<512, 256, 0, stream>>>(wq, wk, wv, wo, wqt, wkt, wvt, wot);
  qkv_gemm<<<dim3(128, 3), 256, 0, stream>>>(x, wqt, wkt, wvt, Qh, Kh, Vt);
  attn_partial<<<dim3(16, 32, 4), 256, 0, stream>>>(Qh, Kh, Vt, Opart, Ml);
  attn_combine<<<2048, 256, 0, stream>>>(Opart, Ml, ctxh);
  out_gemm<<<dim3(128, 8), 256, 0, stream>>>(ctxh, wot, out);
}

// Round 7
// 164.284 us; speedup vs baseline: 1.2232x; 1.1054x over previous
//
#include <hip/hip_runtime.h>
#include <hip/hip_bf16.h>
#include <math.h>

typedef _Float16 half8 __attribute__((ext_vector_type(8)));
typedef _Float16 half4_t __attribute__((ext_vector_type(4)));
typedef _Float16 half2_t __attribute__((ext_vector_type(2)));
typedef float floatx4 __attribute__((ext_vector_type(4)));
typedef float floatx2 __attribute__((ext_vector_type(2)));

#define MFMA16(a, b, c) __builtin_amdgcn_mfma_f32_16x16x32_f16(a, b, c, 0, 0, 0)
#define MASKVAL (-30000.0f)
// 1/sqrt(128) * log2(e), folded into wqt during prep
#define QSCALE 0.1275261529f

// ---------------------------------------------------------------------------
// Kernel 1: coalesced LDS-tiled weight transpose + fp32->fp16 convert.
// ---------------------------------------------------------------------------
__global__ __launch_bounds__(256) void wprep(
    const float* __restrict__ wq, const float* __restrict__ wk,
    const float* __restrict__ wv, const float* __restrict__ wo,
    _Float16* __restrict__ wqt, _Float16* __restrict__ wkt,
    _Float16* __restrict__ wvt, _Float16* __restrict__ wot) {
  __shared__ float T[32][36];
  int bx = blockIdx.x, tid = threadIdx.x;
  const float* src;
  _Float16* dst;
  int R, C, r0, c0;
  float sc = 1.0f;
  if (bx < 384) {
    int p = bx >> 7, t = bx & 127;
    src = (p == 0) ? wq : (p == 1) ? wk : wv;
    dst = (p == 0) ? wqt : (p == 1) ? wkt : wvt;
    if (p == 0) sc = QSCALE;
    R = 1024; C = 128;
    r0 = (t & 31) * 32; c0 = (t >> 5) * 32;
  } else {
    int t = bx - 384;
    src = wo; dst = wot;
    R = 128; C = 1024;
    r0 = (t & 3) * 32; c0 = (t >> 2) * 32;
  }
  {
    int row = tid >> 3, c4 = (tid & 7) * 4;
    float4 f = *(const float4*)&src[(size_t)(r0 + row) * C + c0 + c4];
    T[row][c4] = f.x; T[row][c4 + 1] = f.y; T[row][c4 + 2] = f.z; T[row][c4 + 3] = f.w;
  }
  __syncthreads();
  {
    int cc = tid >> 3, r4 = (tid & 7) * 4;
    half4_t h;
    h[0] = (_Float16)(T[r4 + 0][cc] * sc);
    h[1] = (_Float16)(T[r4 + 1][cc] * sc);
    h[2] = (_Float16)(T[r4 + 2][cc] * sc);
    h[3] = (_Float16)(T[r4 + 3][cc] * sc);
    *(half4_t*)&dst[(size_t)(c0 + cc) * R + r0 + r4] = h;
  }
}

// ---------------------------------------------------------------------------
// Kernel 2: QKV projection, 32-row tiles, grid (256 m-tiles, 3 proj) = 768
// blocks (~3/CU). x converted fp32->fp16 in-register during A-staging.
// V written transposed Vt[(b*128+h)*2048+s]. Wave w: m-sub (w>>1), n-half (w&1).
// ---------------------------------------------------------------------------
__global__ __launch_bounds__(256) void qkv_gemm(
    const float* __restrict__ x, const _Float16* __restrict__ wqt,
    const _Float16* __restrict__ wkt, const _Float16* __restrict__ wvt,
    _Float16* __restrict__ Qh, _Float16* __restrict__ Kh,
    _Float16* __restrict__ Vt) {
  __shared__ _Float16 A_lds[32 * 72];
  __shared__ _Float16 B_lds[128 * 72];
  int tid = threadIdx.x;
  int w = tid >> 6, lane = tid & 63, quad = lane >> 4, l16 = lane & 15;
  int m0 = blockIdx.x * 32;
  int proj = blockIdx.y;
  const _Float16* wt = (proj == 0) ? wqt : (proj == 1) ? wkt : wvt;
  floatx4 zero = {0.f, 0.f, 0.f, 0.f};
  floatx4 acc[4];
#pragma unroll
  for (int t = 0; t < 4; t++) acc[t] = zero;

  int arow = tid >> 3, ak8 = (tid & 7) * 8;
  int brow = tid >> 1, bk32 = (tid & 1) * 32;
  int mw = (w >> 1) * 16, nw = (w & 1) * 64;

  for (int k0 = 0; k0 < 1024; k0 += 64) {
    {
      const float* s = x + (size_t)(m0 + arow) * 1024 + k0 + ak8;
      float4 f0 = *(const float4*)(s);
      float4 f1 = *(const float4*)(s + 4);
      half8 h;
      h[0] = (_Float16)f0.x; h[1] = (_Float16)f0.y; h[2] = (_Float16)f0.z; h[3] = (_Float16)f0.w;
      h[4] = (_Float16)f1.x; h[5] = (_Float16)f1.y; h[6] = (_Float16)f1.z; h[7] = (_Float16)f1.w;
      *(half8*)&A_lds[arow * 72 + ak8] = h;
    }
#pragma unroll
    for (int i = 0; i < 4; i++)
      *(half8*)&B_lds[brow * 72 + bk32 + i * 8] =
          *(const half8*)&wt[(size_t)brow * 1024 + k0 + bk32 + i * 8];
    __syncthreads();
    half8 a[2];
#pragma unroll
    for (int c = 0; c < 2; c++)
      a[c] = *(const half8*)&A_lds[(mw + l16) * 72 + c * 32 + quad * 8];
#pragma unroll
    for (int t = 0; t < 4; t++)
#pragma unroll
      for (int c = 0; c < 2; c++) {
        half8 b = *(const half8*)&B_lds[(nw + t * 16 + l16) * 72 + c * 32 + quad * 8];
        acc[t] = MFMA16(a[c], b, acc[t]);
      }
    __syncthreads();
  }
#pragma unroll
  for (int t = 0; t < 4; t++)
#pragma unroll
    for (int r = 0; r < 4; r++) {
      int row = m0 + mw + quad * 4 + r;
      int col = nw + t * 16 + l16;
      _Float16 v = (_Float16)acc[t][r];
      if (proj == 0)
        Qh[(size_t)row * 128 + col] = v;
      else if (proj == 1)
        Kh[(size_t)row * 128 + col] = v;
      else {
        int bb = row >> 11, s = row & 2047;
        Vt[((size_t)(bb * 128 + col)) * 2048 + s] = v;
      }
    }
}

// ---------------------------------------------------------------------------
// Kernel 3: flash-attention partial, one 128-key chunk per block.
// Exact 1088-block 1D grid (no dead blocks), heavy chunks first.
// K staged in LDS; V prefetched to REGISTERS during K-phase, then dumped into
// the SAME LDS buffer after softmax (sequential phases share 34.8 KB).
// P in its own 17.4 KB region. Total 52.2 KB -> 3 blocks/CU. No global load
// on any MFMA critical path.
// ---------------------------------------------------------------------------
__global__ __launch_bounds__(256, 3) void attn_partial(
    const _Float16* __restrict__ Qh, const _Float16* __restrict__ Kh,
    const _Float16* __restrict__ Vt, _Float16* __restrict__ Opart,
    float* __restrict__ Ml) {
  __shared__ _Float16 KV_lds[128 * 136];  // K (key-major), then V (feat-major)
  __shared__ _Float16 P_lds[4 * 16 * 136];
  int tid = threadIdx.x;
  int w = tid >> 6, lane = tid & 63, quad = lane >> 4, l16 = lane & 15;
  // decode (b, qt, kc) from linear id; r=271-.. puts heavy chunks first.
  // cum(2m)=m(m+1), cum(2m+1)=(m+1)^2, nkc(qt)=qt/2+1, 272 chunks/batch.
  int g = (int)blockIdx.x;
  int b = g & 3;
  int r = 271 - (g >> 2);
  int m = (int)sqrtf((float)r + 1.0f);
  while (m * (m + 1) > r) m--;
  while ((m + 1) * (m + 2) <= r) m++;
  int s1 = (m + 1) * (m + 1);
  int qt, kc;
  if (r >= s1) { qt = 2 * m + 1; kc = r - s1; }
  else         { qt = 2 * m;     kc = r - m * (m + 1); }
  int q0 = qt * 64, k0 = kc * 128;
  int qw0 = q0 + w * 16;
  int sidx = (b * 32 + qt) * 16 + kc;

  const _Float16* Kb = Kh + (size_t)b * 2048 * 128;
  const _Float16* Vb = Vt + (size_t)b * 128 * 2048;

  int srow = tid >> 1, scol = (tid & 1) * 64;
  // stage K chunk (128 keys x 128 feat) into LDS
#pragma unroll
  for (int i = 0; i < 8; i++)
    *(half8*)&KV_lds[srow * 136 + scol + i * 8] =
        *(const half8*)&Kb[(size_t)(k0 + srow) * 128 + scol + i * 8];
  // prefetch V chunk (128 feat x 128 keys) into registers — latency hidden
  // under the entire QK + softmax phase
  half8 vreg[8];
#pragma unroll
  for (int i = 0; i < 8; i++)
    vreg[i] = *(const half8*)&Vb[(size_t)srow * 2048 + k0 + scol + i * 8];

  half8 aq[4];
  {
    const _Float16* qbase = Qh + (size_t)(b * 2048 + qw0 + l16) * 128;
#pragma unroll
    for (int c = 0; c < 4; c++) aq[c] = *(const half8*)&qbase[c * 32 + quad * 8];
  }
  __syncthreads();

  // QK^T: 8 subtiles of 16 keys from LDS
  floatx4 zero = {0.f, 0.f, 0.f, 0.f};
  floatx4 sa[8];
#pragma unroll
  for (int t = 0; t < 8; t++) sa[t] = zero;
#pragma unroll
  for (int t = 0; t < 8; t++)
#pragma unroll
    for (int c = 0; c < 4; c++) {
      half8 bk = *(const half8*)&KV_lds[(t * 16 + l16) * 136 + c * 32 + quad * 8];
      sa[t] = MFMA16(aq[c], bk, sa[t]);
    }

  // chunk-local softmax (branchless causal mask; exp2 underflow -> 0)
  float m_r[4], l_r[4];
#pragma unroll
  for (int r2 = 0; r2 < 4; r2++) {
    int query = qw0 + quad * 4 + r2;
    float mx = MASKVAL;
#pragma unroll
    for (int t = 0; t < 8; t++) {
      float s = (k0 + t * 16 + l16 > query) ? MASKVAL : sa[t][r2];
      sa[t][r2] = s;
      mx = fmaxf(mx, s);
    }
#pragma unroll
    for (int off = 1; off < 16; off <<= 1) mx = fmaxf(mx, __shfl_xor(mx, off));
    float rs = 0.f;
#pragma unroll
    for (int t = 0; t < 8; t++) {
      float e = exp2f(sa[t][r2] - mx);
      sa[t][r2] = e;
      rs += e;
    }
#pragma unroll
    for (int off = 1; off < 16; off <<= 1) rs += __shfl_xor(rs, off);
    m_r[r2] = mx;
    l_r[r2] = rs;
  }

  __syncthreads();  // all waves done reading K from KV_lds

  // dump prefetched V regs into KV_lds (feat-major), zero-latency
#pragma unroll
  for (int i = 0; i < 8; i++)
    *(half8*)&KV_lds[srow * 136 + scol + i * 8] = vreg[i];
  // P: C-layout -> LDS (wave-private region)
  _Float16* P = P_lds + w * 16 * 136;
#pragma unroll
  for (int r2 = 0; r2 < 4; r2++)
#pragma unroll
    for (int t = 0; t < 8; t++)
      P[(quad * 4 + r2) * 136 + t * 16 + l16] = (_Float16)sa[t][r2];
  __syncthreads();  // V visible to all waves

  // PV: both operands from LDS
  floatx4 O[8];
#pragma unroll
  for (int t = 0; t < 8; t++) O[t] = zero;
#pragma unroll
  for (int c2 = 0; c2 < 4; c2++) {
    half8 ap = *(const half8*)&P[l16 * 136 + c2 * 32 + quad * 8];
#pragma unroll
    for (int t = 0; t < 8; t++) {
      half8 bv = *(const half8*)&KV_lds[(t * 16 + l16) * 136 + c2 * 32 + quad * 8];
      O[t] = MFMA16(ap, bv, O[t]);
    }
  }

  size_t obase = (size_t)sidx * 8192;
#pragma unroll
  for (int t = 0; t < 8; t++)
#pragma unroll
    for (int r2 = 0; r2 < 4; r2++)
      Opart[obase + (size_t)(w * 16 + quad * 4 + r2) * 128 + t * 16 + l16] = (_Float16)O[t][r2];
  if (l16 == 0)
#pragma unroll
    for (int r2 = 0; r2 < 4; r2++) {
      int row = w * 16 + quad * 4 + r2;
      floatx2 ml;
      ml[0] = m_r[r2];
      ml[1] = l_r[r2];
      *(floatx2*)&Ml[(size_t)sidx * 128 + row * 2] = ml;
    }
}

// ---------------------------------------------------------------------------
// Kernel 3b: combine partials (up to 16/row). One wave per query row.
// ---------------------------------------------------------------------------
__global__ __launch_bounds__(256) void attn_combine(
    const _Float16* __restrict__ Opart, const float* __restrict__ Ml,
    _Float16* __restrict__ ctx) {
  int tid = threadIdx.x;
  int w = tid >> 6, lane = tid & 63;
  int row = blockIdx.x * 4 + w;
  int b = row >> 11, s = row & 2047;
  int qt = s >> 6, ri = s & 63;
  int nkc = (qt + 2) >> 1;
  int sidx0 = (b * 32 + qt) * 16;
  float M = MASKVAL;
  for (int i = 0; i < nkc; i++)
    M = fmaxf(M, Ml[(size_t)(sidx0 + i) * 128 + ri * 2]);
  float L = 0.f, a0 = 0.f, a1 = 0.f;
  for (int i = 0; i < nkc; i++) {
    float mi = Ml[(size_t)(sidx0 + i) * 128 + ri * 2];
    float li = Ml[(size_t)(sidx0 + i) * 128 + ri * 2 + 1];
    float sc = exp2f(mi - M);
    L += li * sc;
    half2_t o = *(const half2_t*)&Opart[(size_t)(sidx0 + i) * 8192 + (size_t)ri * 128 + lane * 2];
    a0 += sc * (float)o[0];
    a1 += sc * (float)o[1];
  }
  float inv = 1.f / L;
  half2_t hv;
  hv[0] = (_Float16)(a0 * inv);
  hv[1] = (_Float16)(a1 * inv);
  *(half2_t*)&ctx[(size_t)row * 128 + lane * 2] = hv;
}

// ---------------------------------------------------------------------------
// Kernel 4: out projection ctx[8192,128] x wo[128,1024] -> fp32 out.
// ---------------------------------------------------------------------------
__global__ __launch_bounds__(256) void out_gemm(
    const _Float16* __restrict__ ctx, const _Float16* __restrict__ wot,
    float* __restrict__ out) {
  __shared__ _Float16 A_lds[64 * 136];
  __shared__ _Float16 B_lds[128 * 136];
  int tid = threadIdx.x;
  int w = tid >> 6, lane = tid & 63, quad = lane >> 4, l16 = lane & 15;
  int m0 = blockIdx.x * 64, n0 = blockIdx.y * 128;
  {
    int row = tid >> 2, kk = (tid & 3) * 32;
#pragma unroll
    for (int i = 0; i < 4; i++)
      *(half8*)&A_lds[row * 136 + kk + i * 8] =
          *(const half8*)&ctx[(size_t)(m0 + row) * 128 + kk + i * 8];
  }
  {
    int n = tid >> 1, kk = (tid & 1) * 64;
#pragma unroll
    for (int i = 0; i < 8; i++)
      *(half8*)&B_lds[n * 136 + kk + i * 8] =
          *(const half8*)&wot[(size_t)(n0 + n) * 128 + kk + i * 8];
  }
  __syncthreads();
  floatx4 zero = {0.f, 0.f, 0.f, 0.f};
  floatx4 acc[8];
#pragma unroll
  for (int t = 0; t < 8; t++) acc[t] = zero;
  half8 a[4];
#pragma unroll
  for (int c = 0; c < 4; c++) a[c] = *(const half8*)&A_lds[(w * 16 + l16) * 136 + c * 32 + quad * 8];
#pragma unroll
  for (int t = 0; t < 8; t++)
#pragma unroll
    for (int c = 0; c < 4; c++) {
      half8 b = *(const half8*)&B_lds[(t * 16 + l16) * 136 + c * 32 + quad * 8];
      acc[t] = MFMA16(a[c], b, acc[t]);
    }
#pragma unroll
  for (int t = 0; t < 8; t++)
#pragma unroll
    for (int r = 0; r < 4; r++) {
      int row = m0 + w * 16 + quad * 4 + r;
      out[(size_t)row * 1024 + n0 + t * 16 + l16] = acc[t][r];
    }
}

// ---------------------------------------------------------------------------
extern "C" void kernel_launch(void* const* d_in, const int* in_sizes, int n_in,
                              void* d_out, int out_size, void* d_ws, size_t ws_size,
                              hipStream_t stream) {
  const float* x = (const float*)d_in[0];
  const float* wq = (const float*)d_in[1];
  const float* wk = (const float*)d_in[2];
  const float* wv = (const float*)d_in[3];
  const float* wo = (const float*)d_in[4];
  char* ws = (char*)d_ws;
  _Float16* wqt = (_Float16*)(ws + 0);
  _Float16* wkt = (_Float16*)(ws + 262144);
  _Float16* wvt = (_Float16*)(ws + 524288);
  _Float16* wot = (_Float16*)(ws + 786432);
  _Float16* Qh  = (_Float16*)(ws + 1048576);              // 2 MB
  _Float16* Kh  = (_Float16*)(ws + 3145728);              // 2 MB
  _Float16* Vt  = (_Float16*)(ws + 5242880);              // 2 MB
  _Float16* ctxh = (_Float16*)(ws + 7340032);             // 2 MB
  _Float16* Opart = (_Float16*)(ws + 9437184);            // 2048 x 16 KB = 32 MB
  float* Ml = (float*)(ws + 42991616);                    // 1 MB
  float* out = (float*)d_out;

  wprep<<<512, 256, 0, stream>>>(wq, wk, wv, wo, wqt, wkt, wvt, wot);
  qkv_gemm<<<dim3(256, 3), 256, 0, stream>>>(x, wqt, wkt, wvt, Qh, Kh, Vt);
  attn_partial<<<1088, 256, 0, stream>>>(Qh, Kh, Vt, Opart, Ml);
  attn_combine<<<2048, 256, 0, stream>>>(Opart, Ml, ctxh);
  out_gemm<<<dim3(128, 8), 256, 0, stream>>>(ctxh, wot, out);
}

// Round 9
// 160.273 us; speedup vs baseline: 1.2538x; 1.0250x over previous
//
#include <hip/hip_runtime.h>
#include <hip/hip_bf16.h>
#include <math.h>

typedef _Float16 half8 __attribute__((ext_vector_type(8)));
typedef _Float16 half4_t __attribute__((ext_vector_type(4)));
typedef _Float16 half2_t __attribute__((ext_vector_type(2)));
typedef float floatx4 __attribute__((ext_vector_type(4)));
typedef float floatx2 __attribute__((ext_vector_type(2)));

#define MFMA16(a, b, c) __builtin_amdgcn_mfma_f32_16x16x32_f16(a, b, c, 0, 0, 0)
#define MASKVAL (-30000.0f)
// 1/sqrt(128) * log2(e), folded into wqt during prep
#define QSCALE 0.1275261529f

// ---------------------------------------------------------------------------
// Kernel 1: coalesced LDS-tiled weight transpose + fp32->fp16 convert.
// ---------------------------------------------------------------------------
__global__ __launch_bounds__(256) void wprep(
    const float* __restrict__ wq, const float* __restrict__ wk,
    const float* __restrict__ wv, const float* __restrict__ wo,
    _Float16* __restrict__ wqt, _Float16* __restrict__ wkt,
    _Float16* __restrict__ wvt, _Float16* __restrict__ wot) {
  __shared__ float T[32][36];
  int bx = blockIdx.x, tid = threadIdx.x;
  const float* src;
  _Float16* dst;
  int R, C, r0, c0;
  float sc = 1.0f;
  if (bx < 384) {
    int p = bx >> 7, t = bx & 127;
    src = (p == 0) ? wq : (p == 1) ? wk : wv;
    dst = (p == 0) ? wqt : (p == 1) ? wkt : wvt;
    if (p == 0) sc = QSCALE;
    R = 1024; C = 128;
    r0 = (t & 31) * 32; c0 = (t >> 5) * 32;
  } else {
    int t = bx - 384;
    src = wo; dst = wot;
    R = 128; C = 1024;
    r0 = (t & 3) * 32; c0 = (t >> 2) * 32;
  }
  {
    int row = tid >> 3, c4 = (tid & 7) * 4;
    float4 f = *(const float4*)&src[(size_t)(r0 + row) * C + c0 + c4];
    T[row][c4] = f.x; T[row][c4 + 1] = f.y; T[row][c4 + 2] = f.z; T[row][c4 + 3] = f.w;
  }
  __syncthreads();
  {
    int cc = tid >> 3, r4 = (tid & 7) * 4;
    half4_t h;
    h[0] = (_Float16)(T[r4 + 0][cc] * sc);
    h[1] = (_Float16)(T[r4 + 1][cc] * sc);
    h[2] = (_Float16)(T[r4 + 2][cc] * sc);
    h[3] = (_Float16)(T[r4 + 3][cc] * sc);
    *(half4_t*)&dst[(size_t)(c0 + cc) * R + r0 + r4] = h;
  }
}

// ---------------------------------------------------------------------------
// Kernel 2: QKV projection v3 (fixed). 32-row x 128-col tiles, BK=128
// (8 iterations), grid (256, 3) = 768 blocks = 3/CU. Register prefetch
// double-buffer: next iteration's A (4xfloat4) + B (8xhalf8 = full 64-half
// span) loaded right after the barrier so global latency overlaps the MFMA
// phase. LDS stride 136. V written transposed Vt[(b*128+h)*2048+s].
// ---------------------------------------------------------------------------
__global__ __launch_bounds__(256, 3) void qkv_gemm(
    const float* __restrict__ x, const _Float16* __restrict__ wqt,
    const _Float16* __restrict__ wkt, const _Float16* __restrict__ wvt,
    _Float16* __restrict__ Qh, _Float16* __restrict__ Kh,
    _Float16* __restrict__ Vt) {
  __shared__ _Float16 A_lds[32 * 136];
  __shared__ _Float16 B_lds[128 * 136];
  int tid = threadIdx.x;
  int w = tid >> 6, lane = tid & 63, quad = lane >> 4, l16 = lane & 15;
  int m0 = blockIdx.x * 32;
  int proj = blockIdx.y;
  const _Float16* wt = (proj == 0) ? wqt : (proj == 1) ? wkt : wvt;
  floatx4 zero = {0.f, 0.f, 0.f, 0.f};
  floatx4 acc[4];
#pragma unroll
  for (int t = 0; t < 4; t++) acc[t] = zero;

  int arow = tid >> 3, ac0 = (tid & 7) * 16;   // A: 32 rows, 16 floats/thr
  int brow = tid >> 1, bc0 = (tid & 1) * 64;   // B: 128 rows, 64 halfs/thr
  int mw = (w >> 1) * 16, nw = (w & 1) * 64;

  const float* asrc = x + (size_t)(m0 + arow) * 1024 + ac0;
  const _Float16* bsrc = wt + (size_t)brow * 1024 + bc0;

  float4 af[4];
  half8 bf[8];
#pragma unroll
  for (int i = 0; i < 4; i++) af[i] = ((const float4*)asrc)[i];
#pragma unroll
  for (int i = 0; i < 8; i++) bf[i] = ((const half8*)bsrc)[i];

  for (int k0 = 0; k0 < 1024; k0 += 128) {
    // dump staged registers to LDS (convert A fp32->fp16)
    {
      half8 h0, h1;
      h0[0] = (_Float16)af[0].x; h0[1] = (_Float16)af[0].y;
      h0[2] = (_Float16)af[0].z; h0[3] = (_Float16)af[0].w;
      h0[4] = (_Float16)af[1].x; h0[5] = (_Float16)af[1].y;
      h0[6] = (_Float16)af[1].z; h0[7] = (_Float16)af[1].w;
      h1[0] = (_Float16)af[2].x; h1[1] = (_Float16)af[2].y;
      h1[2] = (_Float16)af[2].z; h1[3] = (_Float16)af[2].w;
      h1[4] = (_Float16)af[3].x; h1[5] = (_Float16)af[3].y;
      h1[6] = (_Float16)af[3].z; h1[7] = (_Float16)af[3].w;
      *(half8*)&A_lds[arow * 136 + ac0] = h0;
      *(half8*)&A_lds[arow * 136 + ac0 + 8] = h1;
    }
#pragma unroll
    for (int i = 0; i < 8; i++)
      *(half8*)&B_lds[brow * 136 + bc0 + i * 8] = bf[i];
    __syncthreads();

    // prefetch next k-slice into registers (latency overlaps MFMA phase)
    if (k0 + 128 < 1024) {
      const float* a2 = asrc + k0 + 128;
      const _Float16* b2 = bsrc + k0 + 128;
#pragma unroll
      for (int i = 0; i < 4; i++) af[i] = ((const float4*)a2)[i];
#pragma unroll
      for (int i = 0; i < 8; i++) bf[i] = ((const half8*)b2)[i];
    }

    half8 a[4];
#pragma unroll
    for (int c = 0; c < 4; c++)
      a[c] = *(const half8*)&A_lds[(mw + l16) * 136 + c * 32 + quad * 8];
#pragma unroll
    for (int t = 0; t < 4; t++)
#pragma unroll
      for (int c = 0; c < 4; c++) {
        half8 b = *(const half8*)&B_lds[(nw + t * 16 + l16) * 136 + c * 32 + quad * 8];
        acc[t] = MFMA16(a[c], b, acc[t]);
      }
    __syncthreads();
  }
#pragma unroll
  for (int t = 0; t < 4; t++)
#pragma unroll
    for (int r = 0; r < 4; r++) {
      int row = m0 + mw + quad * 4 + r;
      int col = nw + t * 16 + l16;
      _Float16 v = (_Float16)acc[t][r];
      if (proj == 0)
        Qh[(size_t)row * 128 + col] = v;
      else if (proj == 1)
        Kh[(size_t)row * 128 + col] = v;
      else {
        int bb = row >> 11, s = row & 2047;
        Vt[((size_t)(bb * 128 + col)) * 2048 + s] = v;
      }
    }
}

// ---------------------------------------------------------------------------
// Kernel 3: flash-attention partial, one 128-key chunk per block.
// Exact 1088-block 1D grid (no dead blocks), heavy chunks first.
// K staged in LDS; V prefetched to REGISTERS during K-phase, then dumped into
// the SAME LDS buffer after softmax. 52.2 KB -> 3 blocks/CU.
// ---------------------------------------------------------------------------
__global__ __launch_bounds__(256, 3) void attn_partial(
    const _Float16* __restrict__ Qh, const _Float16* __restrict__ Kh,
    const _Float16* __restrict__ Vt, _Float16* __restrict__ Opart,
    float* __restrict__ Ml) {
  __shared__ _Float16 KV_lds[128 * 136];  // K (key-major), then V (feat-major)
  __shared__ _Float16 P_lds[4 * 16 * 136];
  int tid = threadIdx.x;
  int w = tid >> 6, lane = tid & 63, quad = lane >> 4, l16 = lane & 15;
  int g = (int)blockIdx.x;
  int b = g & 3;
  int r = 271 - (g >> 2);
  int m = (int)sqrtf((float)r + 1.0f);
  while (m * (m + 1) > r) m--;
  while ((m + 1) * (m + 2) <= r) m++;
  int s1 = (m + 1) * (m + 1);
  int qt, kc;
  if (r >= s1) { qt = 2 * m + 1; kc = r - s1; }
  else         { qt = 2 * m;     kc = r - m * (m + 1); }
  int q0 = qt * 64, k0 = kc * 128;
  int qw0 = q0 + w * 16;
  int sidx = (b * 32 + qt) * 16 + kc;

  const _Float16* Kb = Kh + (size_t)b * 2048 * 128;
  const _Float16* Vb = Vt + (size_t)b * 128 * 2048;

  int srow = tid >> 1, scol = (tid & 1) * 64;
#pragma unroll
  for (int i = 0; i < 8; i++)
    *(half8*)&KV_lds[srow * 136 + scol + i * 8] =
        *(const half8*)&Kb[(size_t)(k0 + srow) * 128 + scol + i * 8];
  half8 vreg[8];
#pragma unroll
  for (int i = 0; i < 8; i++)
    vreg[i] = *(const half8*)&Vb[(size_t)srow * 2048 + k0 + scol + i * 8];

  half8 aq[4];
  {
    const _Float16* qbase = Qh + (size_t)(b * 2048 + qw0 + l16) * 128;
#pragma unroll
    for (int c = 0; c < 4; c++) aq[c] = *(const half8*)&qbase[c * 32 + quad * 8];
  }
  __syncthreads();

  floatx4 zero = {0.f, 0.f, 0.f, 0.f};
  floatx4 sa[8];
#pragma unroll
  for (int t = 0; t < 8; t++) sa[t] = zero;
#pragma unroll
  for (int t = 0; t < 8; t++)
#pragma unroll
    for (int c = 0; c < 4; c++) {
      half8 bk = *(const half8*)&KV_lds[(t * 16 + l16) * 136 + c * 32 + quad * 8];
      sa[t] = MFMA16(aq[c], bk, sa[t]);
    }

  float m_r[4], l_r[4];
#pragma unroll
  for (int r2 = 0; r2 < 4; r2++) {
    int query = qw0 + quad * 4 + r2;
    float mx = MASKVAL;
#pragma unroll
    for (int t = 0; t < 8; t++) {
      float s = (k0 + t * 16 + l16 > query) ? MASKVAL : sa[t][r2];
      sa[t][r2] = s;
      mx = fmaxf(mx, s);
    }
#pragma unroll
    for (int off = 1; off < 16; off <<= 1) mx = fmaxf(mx, __shfl_xor(mx, off));
    float rs = 0.f;
#pragma unroll
    for (int t = 0; t < 8; t++) {
      float e = exp2f(sa[t][r2] - mx);
      sa[t][r2] = e;
      rs += e;
    }
#pragma unroll
    for (int off = 1; off < 16; off <<= 1) rs += __shfl_xor(rs, off);
    m_r[r2] = mx;
    l_r[r2] = rs;
  }

  __syncthreads();  // all waves done reading K from KV_lds

#pragma unroll
  for (int i = 0; i < 8; i++)
    *(half8*)&KV_lds[srow * 136 + scol + i * 8] = vreg[i];
  _Float16* P = P_lds + w * 16 * 136;
#pragma unroll
  for (int r2 = 0; r2 < 4; r2++)
#pragma unroll
    for (int t = 0; t < 8; t++)
      P[(quad * 4 + r2) * 136 + t * 16 + l16] = (_Float16)sa[t][r2];
  __syncthreads();  // V visible to all waves

  floatx4 O[8];
#pragma unroll
  for (int t = 0; t < 8; t++) O[t] = zero;
#pragma unroll
  for (int c2 = 0; c2 < 4; c2++) {
    half8 ap = *(const half8*)&P[l16 * 136 + c2 * 32 + quad * 8];
#pragma unroll
    for (int t = 0; t < 8; t++) {
      half8 bv = *(const half8*)&KV_lds[(t * 16 + l16) * 136 + c2 * 32 + quad * 8];
      O[t] = MFMA16(ap, bv, O[t]);
    }
  }

  size_t obase = (size_t)sidx * 8192;
#pragma unroll
  for (int t = 0; t < 8; t++)
#pragma unroll
    for (int r2 = 0; r2 < 4; r2++)
      Opart[obase + (size_t)(w * 16 + quad * 4 + r2) * 128 + t * 16 + l16] = (_Float16)O[t][r2];
  if (l16 == 0)
#pragma unroll
    for (int r2 = 0; r2 < 4; r2++) {
      int row = w * 16 + quad * 4 + r2;
      floatx2 ml;
      ml[0] = m_r[r2];
      ml[1] = l_r[r2];
      *(floatx2*)&Ml[(size_t)sidx * 128 + row * 2] = ml;
    }
}

// ---------------------------------------------------------------------------
// Kernel 3b: combine partials (up to 16/row). One wave per query row.
// ---------------------------------------------------------------------------
__global__ __launch_bounds__(256) void attn_combine(
    const _Float16* __restrict__ Opart, const float* __restrict__ Ml,
    _Float16* __restrict__ ctx) {
  int tid = threadIdx.x;
  int w = tid >> 6, lane = tid & 63;
  int row = blockIdx.x * 4 + w;
  int b = row >> 11, s = row & 2047;
  int qt = s >> 6, ri = s & 63;
  int nkc = (qt + 2) >> 1;
  int sidx0 = (b * 32 + qt) * 16;
  float M = MASKVAL;
  for (int i = 0; i < nkc; i++)
    M = fmaxf(M, Ml[(size_t)(sidx0 + i) * 128 + ri * 2]);
  float L = 0.f, a0 = 0.f, a1 = 0.f;
  for (int i = 0; i < nkc; i++) {
    float mi = Ml[(size_t)(sidx0 + i) * 128 + ri * 2];
    float li = Ml[(size_t)(sidx0 + i) * 128 + ri * 2 + 1];
    float sc = exp2f(mi - M);
    L += li * sc;
    half2_t o = *(const half2_t*)&Opart[(size_t)(sidx0 + i) * 8192 + (size_t)ri * 128 + lane * 2];
    a0 += sc * (float)o[0];
    a1 += sc * (float)o[1];
  }
  float inv = 1.f / L;
  half2_t hv;
  hv[0] = (_Float16)(a0 * inv);
  hv[1] = (_Float16)(a1 * inv);
  *(half2_t*)&ctx[(size_t)row * 128 + lane * 2] = hv;
}

// ---------------------------------------------------------------------------
// Kernel 4: out projection ctx[8192,128] x wo[128,1024] -> fp32 out.
// ---------------------------------------------------------------------------
__global__ __launch_bounds__(256) void out_gemm(
    const _Float16* __restrict__ ctx, const _Float16* __restrict__ wot,
    float* __restrict__ out) {
  __shared__ _Float16 A_lds[64 * 136];
  __shared__ _Float16 B_lds[128 * 136];
  int tid = threadIdx.x;
  int w = tid >> 6, lane = tid & 63, quad = lane >> 4, l16 = lane & 15;
  int m0 = blockIdx.x * 64, n0 = blockIdx.y * 128;
  {
    int row = tid >> 2, kk = (tid & 3) * 32;
#pragma unroll
    for (int i = 0; i < 4; i++)
      *(half8*)&A_lds[row * 136 + kk + i * 8] =
          *(const half8*)&ctx[(size_t)(m0 + row) * 128 + kk + i * 8];
  }
  {
    int n = tid >> 1, kk = (tid & 1) * 64;
#pragma unroll
    for (int i = 0; i < 8; i++)
      *(half8*)&B_lds[n * 136 + kk + i * 8] =
          *(const half8*)&wot[(size_t)(n0 + n) * 128 + kk + i * 8];
  }
  __syncthreads();
  floatx4 zero = {0.f, 0.f, 0.f, 0.f};
  floatx4 acc[8];
#pragma unroll
  for (int t = 0; t < 8; t++) acc[t] = zero;
  half8 a[4];
#pragma unroll
  for (int c = 0; c < 4; c++) a[c] = *(const half8*)&A_lds[(w * 16 + l16) * 136 + c * 32 + quad * 8];
#pragma unroll
  for (int t = 0; t < 8; t++)
#pragma unroll
    for (int c = 0; c < 4; c++) {
      half8 b = *(const half8*)&B_lds[(t * 16 + l16) * 136 + c * 32 + quad * 8];
      acc[t] = MFMA16(a[c], b, acc[t]);
    }
#pragma unroll
  for (int t = 0; t < 8; t++)
#pragma unroll
    for (int r = 0; r < 4; r++) {
      int row = m0 + w * 16 + quad * 4 + r;
      out[(size_t)row * 1024 + n0 + t * 16 + l16] = acc[t][r];
    }
}

// ---------------------------------------------------------------------------
extern "C" void kernel_launch(void* const* d_in, const int* in_sizes, int n_in,
                              void* d_out, int out_size, void* d_ws, size_t ws_size,
                              hipStream_t stream) {
  const float* x = (const float*)d_in[0];
  const float* wq = (const float*)d_in[1];
  const float* wk = (const float*)d_in[2];
  const float* wv = (const float*)d_in[3];
  const float* wo = (const float*)d_in[4];
  char* ws = (char*)d_ws;
  _Float16* wqt = (_Float16*)(ws + 0);
  _Float16* wkt = (_Float16*)(ws + 262144);
  _Float16* wvt = (_Float16*)(ws + 524288);
  _Float16* wot = (_Float16*)(ws + 786432);
  _Float16* Qh  = (_Float16*)(ws + 1048576);              // 2 MB
  _Float16* Kh  = (_Float16*)(ws + 3145728);              // 2 MB
  _Float16* Vt  = (_Float16*)(ws + 5242880);              // 2 MB
  _Float16* ctxh = (_Float16*)(ws + 7340032);             // 2 MB
  _Float16* Opart = (_Float16*)(ws + 9437184);            // 2048 x 16 KB = 32 MB
  float* Ml = (float*)(ws + 42991616);                    // 1 MB
  float* out = (float*)d_out;

  wprep<<<512, 256, 0, stream>>>(wq, wk, wv, wo, wqt, wkt, wvt, wot);
  qkv_gemm<<<dim3(256, 3), 256, 0, stream>>>(x, wqt, wkt, wvt, Qh, Kh, Vt);
  attn_partial<<<1088, 256, 0, stream>>>(Qh, Kh, Vt, Opart, Ml);
  attn_combine<<<2048, 256, 0, stream>>>(Opart, Ml, ctxh);
  out_gemm<<<dim3(128, 8), 256, 0, stream>>>(ctxh, wot, out);
}